// Round 7
// baseline (515.626 us; speedup 1.0000x reference)
//
#include <hip/hip_runtime.h>
#include <cstdint>
#include <cstddef>

// Problem constants (fixed by the reference file)
#define B_TOT 32768
#define NPART 8
#define NCLUS 512
#define DCL   64
#define DTOT  512
#define BTILE 16
#define ROWB  272   // cimg row bytes: 128B hi + 128B lo + 4B c2 + 12B pad (16B-mult)

typedef _Float16 half8 __attribute__((ext_vector_type(8)));
typedef float    f32x4 __attribute__((ext_vector_type(4)));

// ---------------------------------------------------------------------------
// Threefry-2x32 (exactly jax/_src/prng.py), partitionable scheme (verified R1):
//   split  -> foldlike: key_j = cipher(key, (0, j))
//   bits32 -> per flat index n: bits1 ^ bits2 of cipher(key, (0, n))
// ---------------------------------------------------------------------------
__host__ __device__ __forceinline__ void tf2x32(uint32_t k0, uint32_t k1,
    uint32_t x0, uint32_t x1, uint32_t& o0, uint32_t& o1)
{
  const uint32_t k2 = k0 ^ k1 ^ 0x1BD11BDAu;
#define TFR(r) { x0 += x1; x1 = (x1 << r) | (x1 >> (32 - r)); x1 ^= x0; }
  x0 += k0; x1 += k1;
  TFR(13) TFR(15) TFR(26) TFR(6)
  x0 += k1; x1 += k2 + 1u;
  TFR(17) TFR(29) TFR(16) TFR(24)
  x0 += k2; x1 += k0 + 2u;
  TFR(13) TFR(15) TFR(26) TFR(6)
  x0 += k0; x1 += k1 + 3u;
  TFR(17) TFR(29) TFR(16) TFR(24)
  x0 += k1; x1 += k2 + 4u;
  TFR(13) TFR(15) TFR(26) TFR(6)
  x0 += k2; x1 += k0 + 5u;
#undef TFR
  o0 = x0; o1 = x1;
}

__device__ __forceinline__ uint32_t tf_bits32(uint32_t k0, uint32_t k1, uint32_t n)
{
  uint32_t a, b;
  tf2x32(k0, k1, 0u, n, a, b);
  return a ^ b;
}

// XLA ErfInv32 (Giles polynomial) — matches xla math.cc
__device__ __forceinline__ float erfinv_xla(float x)
{
  float w = -log1pf(-x * x);
  float p;
  if (w < 5.0f) {
    w = w - 2.5f;
    p = 2.81022636e-08f;
    p = fmaf(p, w, 3.43273939e-07f);
    p = fmaf(p, w, -3.5233877e-06f);
    p = fmaf(p, w, -4.39150654e-06f);
    p = fmaf(p, w, 0.00021858087f);
    p = fmaf(p, w, -0.00125372503f);
    p = fmaf(p, w, -0.00417768164f);
    p = fmaf(p, w, 0.246640727f);
    p = fmaf(p, w, 1.50140941f);
  } else {
    w = __builtin_amdgcn_sqrtf(w) - 3.0f;
    p = -0.000200214257f;
    p = fmaf(p, w, 0.000100950558f);
    p = fmaf(p, w, 0.00134934322f);
    p = fmaf(p, w, -0.00367342844f);
    p = fmaf(p, w, 0.00573950773f);
    p = fmaf(p, w, -0.0076224613f);
    p = fmaf(p, w, 0.00943887047f);
    p = fmaf(p, w, 1.00167406f);
    p = fmaf(p, w, 2.83297682f);
  }
  return p * x;
}

// ---------------------------------------------------------------------------
// Prep: per centroid row (p*512+c): fp16 hi/lo split + c2 (same fmaf order as
// R2-R4 — passed repeatedly), packed in one 272-byte row: [hi 128B | lo 128B | c2].
// ---------------------------------------------------------------------------
__global__ __launch_bounds__(256) void qvae_prep_kernel(
    const float* __restrict__ centroids, _Float16* __restrict__ cimg)
{
  const int idx = blockIdx.x * 256 + threadIdx.x;   // 0..4095
  const float* row = centroids + (size_t)idx * DCL;
  _Float16* orow = (_Float16*)((char*)cimg + (size_t)idx * ROWB);
  float s = 0.f;
#pragma unroll
  for (int d = 0; d < DCL; d += 4) {
    const float4 v = *(const float4*)(row + d);
    s = fmaf(v.x, v.x, s);
    s = fmaf(v.y, v.y, s);
    s = fmaf(v.z, v.z, s);
    s = fmaf(v.w, v.w, s);
  }
  *(float*)(orow + 128) = s;
#pragma unroll
  for (int d = 0; d < DCL; d += 8) {
    const float4 v0 = *(const float4*)(row + d);
    const float4 v1 = *(const float4*)(row + d + 4);
    const float vv[8] = { v0.x, v0.y, v0.z, v0.w, v1.x, v1.y, v1.z, v1.w };
    half8 hh, ll;
#pragma unroll
    for (int j = 0; j < 8; ++j) {
      const _Float16 h = (_Float16)vv[j];
      hh[j] = h;
      ll[j] = (_Float16)(vv[j] - (float)h);
    }
    *(half8*)(orow + d) = hh;
    *(half8*)(orow + 64 + d) = ll;
  }
}

// ---------------------------------------------------------------------------
// Main kernel — EXACT R4 configuration (VGPR 48, 441 us): block = 1 partition
// x 16 users, 4 waves. fp16-split MFMA cross (two independent 3-MFMA chains),
// software-pipelined over 8 column-tiles (2-buffer prefetch from L2-resident
// 272B-row image). Gumbel-argmax + softmax fused. C/D layout: col=lane&15,
// row=(lane>>4)*4+reg (verified). R6 lesson: hoisting the c2 address into a
// separate live value (c2off) shifted regalloc to VGPR 64, occupancy -10pt,
// +5% time — keep c2 addressing INLINE in LOADT.
// ---------------------------------------------------------------------------
__global__ __launch_bounds__(256, 4) void qvae_main_kernel(
    const float* __restrict__ user_emb, const _Float16* __restrict__ cimg,
    const int* __restrict__ user_id, float* __restrict__ out_logits,
    int* __restrict__ sel, uint32_t kg0, uint32_t kg1)
{
  __shared__ float u2s[BTILE];
  __shared__ float zZ[4][BTILE];
  __shared__ float zS[4][BTILE];
  __shared__ int   zA[4][BTILE];

  const int p = blockIdx.y;
  const int bbase = blockIdx.x * BTILE;
  const int tid = threadIdx.x;
  const int w  = tid >> 6;    // wave 0..3
  const int l  = tid & 63;
  const int lr = l & 15;      // A-row / B-col lane index
  const int q  = l >> 4;      // k-quarter

  // ---- A fragments (16 users x 64 dims, fp16 split) + u2 ----
  const int uid = user_id[bbase + lr];
  const float* urow = user_emb + (size_t)uid * DTOT + p * DCL;
  float uf[16];
  {
    const float4 a0 = *(const float4*)(urow + q * 8);
    const float4 a1 = *(const float4*)(urow + q * 8 + 4);
    const float4 a2 = *(const float4*)(urow + 32 + q * 8);
    const float4 a3 = *(const float4*)(urow + 32 + q * 8 + 4);
    uf[0]=a0.x;  uf[1]=a0.y;  uf[2]=a0.z;  uf[3]=a0.w;
    uf[4]=a1.x;  uf[5]=a1.y;  uf[6]=a1.z;  uf[7]=a1.w;
    uf[8]=a2.x;  uf[9]=a2.y;  uf[10]=a2.z; uf[11]=a2.w;
    uf[12]=a3.x; uf[13]=a3.y; uf[14]=a3.z; uf[15]=a3.w;
  }
  half8 ah[2], al[2];
#pragma unroll
  for (int m = 0; m < 2; ++m)
#pragma unroll
    for (int j = 0; j < 8; ++j) {
      const float v = uf[m * 8 + j];
      const _Float16 h = (_Float16)v;
      ah[m][j] = h;
      al[m][j] = (_Float16)(v - (float)h);
    }
  {
    float s = 0.f;
#pragma unroll
    for (int i = 0; i < 16; ++i) s = fmaf(uf[i], uf[i], s);
    s += __shfl_xor(s, 16);
    s += __shfl_xor(s, 32);     // all lanes sharing lr now hold full u2[lr]
    if (tid < BTILE) u2s[tid] = s;
  }
  __syncthreads();
  float u2r[4];
  {
    const float4 uv = *(const float4*)&u2s[q * 4];
    u2r[0]=uv.x; u2r[1]=uv.y; u2r[2]=uv.z; u2r[3]=uv.w;
  }

  // per-wave/lane bases: cluster col = wcol + CDELT(i); threefry n = nbw + ...
  const int wcol = w * 32 + lr;
  const uint32_t nbw =
      ((uint32_t)(bbase + q * 4) * 8u + (uint32_t)p) * 512u + (uint32_t)wcol;
  const char* cb = (const char*)cimg;
  const uint32_t rowoff =
      ((uint32_t)p * NCLUS + (uint32_t)wcol) * (uint32_t)ROWB + (uint32_t)q * 16u;

  float ereg[32];
  float Zs[4]  = { 0.f, 0.f, 0.f, 0.f };
  float smx[4] = { -3.4e38f, -3.4e38f, -3.4e38f, -3.4e38f };
  int   sag[4] = { 0, 0, 0, 0 };

  // cluster-col delta for pipeline step i (tile = (i>>1)*8 + w*2 + (i&1))
#define CDELT(i) ((((i) >> 1) * 128) + (((i) & 1) * 16))
#define BDELT(i) ((uint32_t)(CDELT(i)) * (uint32_t)ROWB)

#define LOADT(S, i)                                                           \
  {                                                                           \
    const uint32_t vo = rowoff + BDELT(i);                                    \
    bh0##S = *(const half8*)(cb + vo);                                        \
    bh1##S = *(const half8*)(cb + vo + 64);                                   \
    bl0##S = *(const half8*)(cb + vo + 128);                                  \
    bl1##S = *(const half8*)(cb + vo + 192);                                  \
    c2##S  = *(const float*)(cb + (vo - q * 16) + 256);                       \
  }

#define COMPT(S, i)                                                           \
  {                                                                           \
    f32x4 accA = { 0.f, 0.f, 0.f, 0.f };                                      \
    f32x4 accB = { 0.f, 0.f, 0.f, 0.f };                                      \
    accA = __builtin_amdgcn_mfma_f32_16x16x32_f16(ah[0], bh0##S, accA, 0, 0, 0);\
    accB = __builtin_amdgcn_mfma_f32_16x16x32_f16(ah[1], bh1##S, accB, 0, 0, 0);\
    accA = __builtin_amdgcn_mfma_f32_16x16x32_f16(al[0], bh0##S, accA, 0, 0, 0);\
    accB = __builtin_amdgcn_mfma_f32_16x16x32_f16(al[1], bh1##S, accB, 0, 0, 0);\
    accA = __builtin_amdgcn_mfma_f32_16x16x32_f16(ah[0], bl0##S, accA, 0, 0, 0);\
    accB = __builtin_amdgcn_mfma_f32_16x16x32_f16(ah[1], bl1##S, accB, 0, 0, 0);\
    const uint32_t ncol = nbw + (uint32_t)CDELT(i);                           \
    const int colc = wcol + CDELT(i);                                         \
    _Pragma("unroll")                                                         \
    for (int r = 0; r < 4; ++r) {                                             \
      const float u2c2 = __fadd_rn(u2r[r], c2##S);                            \
      const float d2 =                                                        \
          fmaxf(fmaf(-2.0f, accA[r], fmaf(-2.0f, accB[r], u2c2)), 0.0f);      \
      const float qd = __builtin_amdgcn_sqrtf(__fadd_rn(d2, 1e-12f));         \
      const uint32_t bits = tf_bits32(kg0, kg1, ncol + (uint32_t)r * 4096u);  \
      const float u01 = __uint_as_float((bits >> 9) | 0x3f800000u) - 1.0f;    \
      const float gu = __fadd_rn(u01, 1e-10f);  /* >=1e-10 always: fmax dropped (exact) */ \
      const float g = -__logf(-__logf(gu));                                   \
      const float sc = __fsub_rn(g, qd);                                      \
      if (sc > smx[r]) { smx[r] = sc; sag[r] = colc; }                        \
      const float e = __expf(-qd);              /* exp(nd), no max-sub */     \
      ereg[(i) * 4 + r] = e;                                                  \
      Zs[r] = __fadd_rn(Zs[r], e);                                            \
    }                                                                         \
  }

  half8 bh0A, bh1A, bl0A, bl1A; float c2A;
  half8 bh0B, bh1B, bl0B, bl1B; float c2B;
  LOADT(A, 0)
  LOADT(B, 1)
  COMPT(A, 0)
  LOADT(A, 2)
  COMPT(B, 1)
  LOADT(B, 3)
  COMPT(A, 2)
  LOADT(A, 4)
  COMPT(B, 3)
  LOADT(B, 5)
  COMPT(A, 4)
  LOADT(A, 6)
  COMPT(B, 5)
  LOADT(B, 7)
  COMPT(A, 6)
  COMPT(B, 7)

  // reduce across the 16 lanes (same q) holding this row set
#pragma unroll
  for (int m = 1; m < 16; m <<= 1) {
#pragma unroll
    for (int r = 0; r < 4; ++r) {
      Zs[r] += __shfl_xor(Zs[r], m);
      const float os = __shfl_xor(smx[r], m);
      const int   oa = __shfl_xor(sag[r], m);
      if (os > smx[r] || (os == smx[r] && oa < sag[r])) { smx[r] = os; sag[r] = oa; }
    }
  }
  if (lr == 0) {
#pragma unroll
    for (int r = 0; r < 4; ++r) {
      zZ[w][q * 4 + r] = Zs[r];
      zS[w][q * 4 + r] = smx[r];
      zA[w][q * 4 + r] = sag[r];
    }
  }
  __syncthreads();

  // cross-wave combine (4 waves hold different cluster columns of same rows)
  float Zf[4]  = { 0.f, 0.f, 0.f, 0.f };
  float smf[4] = { -3.4e38f, -3.4e38f, -3.4e38f, -3.4e38f };
  int   saf[4] = { 0, 0, 0, 0 };
#pragma unroll
  for (int wv = 0; wv < 4; ++wv) {
    const float4 zz = *(const float4*)&zZ[wv][q * 4];
    const float4 ss = *(const float4*)&zS[wv][q * 4];
    const int4   aa = *(const int4*)&zA[wv][q * 4];
    const float zv[4] = { zz.x, zz.y, zz.z, zz.w };
    const float sv[4] = { ss.x, ss.y, ss.z, ss.w };
    const int   av[4] = { aa.x, aa.y, aa.z, aa.w };
#pragma unroll
    for (int r = 0; r < 4; ++r) {
      Zf[r] = __fadd_rn(Zf[r], zv[r]);
      if (sv[r] > smf[r] || (sv[r] == smf[r] && av[r] < saf[r])) {
        smf[r] = sv[r]; saf[r] = av[r];
      }
    }
  }

  float inv[4];
#pragma unroll
  for (int r = 0; r < 4; ++r) inv[r] = __builtin_amdgcn_rcpf(Zf[r]);

  float* obase = out_logits + ((size_t)(bbase + q * 4) * 8 + p) * 512 + wcol;
#pragma unroll
  for (int i = 0; i < 8; ++i)
#pragma unroll
    for (int r = 0; r < 4; ++r)
      obase[(size_t)r * 4096 + CDELT(i)] = ereg[i * 4 + r] * inv[r];

  if (w == 0 && lr == 0) {
#pragma unroll
    for (int r = 0; r < 4; ++r)
      sel[(bbase + q * 4 + r) * NPART + p] = saf[r];
  }
#undef CDELT
#undef BDELT
#undef LOADT
#undef COMPT
}

// ---------------------------------------------------------------------------
// Score kernel (unchanged, passed 6x): one 64-lane wave per b.
// ---------------------------------------------------------------------------
__global__ __launch_bounds__(256) void qvae_score_kernel(
    const float* __restrict__ centroids, const float* __restrict__ item_mu,
    const float* __restrict__ item_logvar, const int* __restrict__ item_id,
    const int* __restrict__ sel, float* __restrict__ out_score,
    uint32_t ke0, uint32_t ke1)
{
  const int lane = threadIdx.x & 63;
  const int b = blockIdx.x * 4 + (threadIdx.x >> 6);
  const int iid = item_id[b];
  const int pp = lane >> 3;
  const int sc = sel[b * NPART + pp];

  const float* cen = centroids + ((size_t)pp * NCLUS + sc) * DCL + (lane & 7) * 8;
  const float* mu = item_mu + (size_t)iid * DTOT + lane * 8;
  const float* lv = item_logvar + (size_t)iid * DTOT + lane * 8;

  const float4 m0 = *(const float4*)mu;
  const float4 m1 = *(const float4*)(mu + 4);
  const float4 l0 = *(const float4*)lv;
  const float4 l1 = *(const float4*)(lv + 4);
  const float4 q0 = *(const float4*)cen;
  const float4 q1 = *(const float4*)(cen + 4);
  const float mua[8] = { m0.x, m0.y, m0.z, m0.w, m1.x, m1.y, m1.z, m1.w };
  const float lva[8] = { l0.x, l0.y, l0.z, l0.w, l1.x, l1.y, l1.z, l1.w };
  const float cna[8] = { q0.x, q0.y, q0.z, q0.w, q1.x, q1.y, q1.z, q1.w };

  const float LO = __int_as_float(0xBF7FFFFFu);   // nextafter(-1,0)
  const float SQ2 = __int_as_float(0x3FB504F3u);  // float(sqrt(2))
  const uint32_t nb = (uint32_t)b * 512u + (uint32_t)lane * 8u;

  float acc = 0.f;
#pragma unroll
  for (int k = 0; k < 8; ++k) {
    const uint32_t bits = tf_bits32(ke0, ke1, nb + (uint32_t)k);
    const float u01 = __uint_as_float((bits >> 9) | 0x3f800000u) - 1.0f;
    const float uu = fmaxf(LO, __fadd_rn(__fmul_rn(u01, 2.0f), LO));
    const float eps = __fmul_rn(SQ2, erfinv_xla(uu));
    const float sd = __expf(__fmul_rn(0.5f, lva[k]));
    const float it = __fadd_rn(__fmul_rn(eps, sd), mua[k]);
    acc = fmaf(cna[k], it, acc);
  }
#pragma unroll
  for (int m = 1; m < 64; m <<= 1) acc += __shfl_xor(acc, m);
  if (lane == 0) out_score[b] = acc;
}

// ---------------------------------------------------------------------------
extern "C" void kernel_launch(void* const* d_in, const int* in_sizes, int n_in,
                              void* d_out, int out_size, void* d_ws, size_t ws_size,
                              hipStream_t stream)
{
  (void)in_sizes; (void)n_in; (void)out_size; (void)ws_size;

  const float* user_emb    = (const float*)d_in[0];
  const float* centroids   = (const float*)d_in[1];
  const float* item_mu     = (const float*)d_in[2];
  const float* item_logvar = (const float*)d_in[3];
  const int*   user_id     = (const int*)d_in[4];
  const int*   item_id     = (const int*)d_in[5];

  float* out_score  = (float*)d_out;            // [B]
  float* out_logits = (float*)d_out + B_TOT;    // [B,P,C]

  // ws layout: sel [B*P] int (1 MB) | cimg [P*C][272B] (1.09 MB, 16B-aligned)
  int*       sel  = (int*)d_ws;
  _Float16*  cimg = (_Float16*)((char*)d_ws + (size_t)B_TOT * NPART * 4);

  // host-side key derivation: key(42) = (0,42); foldlike split
  uint32_t kg0, kg1, ke0, ke1;
  tf2x32(0u, 42u, 0u, 0u, kg0, kg1);
  tf2x32(0u, 42u, 0u, 1u, ke0, ke1);

  qvae_prep_kernel<<<NPART * NCLUS / 256, 256, 0, stream>>>(centroids, cimg);

  dim3 g1(B_TOT / BTILE, NPART);
  qvae_main_kernel<<<g1, 256, 0, stream>>>(user_emb, cimg, user_id,
                                           out_logits, sel, kg0, kg1);
  qvae_score_kernel<<<B_TOT / 4, 256, 0, stream>>>(centroids, item_mu, item_logvar,
                                                   item_id, sel, out_score, ke0, ke1);
}

// Round 8
// 483.215 us; speedup vs baseline: 1.0671x; 1.0671x over previous
//
#include <hip/hip_runtime.h>
#include <cstdint>
#include <cstddef>

// Problem constants (fixed by the reference file)
#define B_TOT 32768
#define NPART 8
#define NCLUS 512
#define DCL   64
#define DTOT  512
#define BTILE 16
#define ROWB  272   // cimg row bytes: 128B hi + 128B lo + 4B c2 + 12B pad (16B-mult)

typedef _Float16 half8 __attribute__((ext_vector_type(8)));
typedef float    f32x4 __attribute__((ext_vector_type(4)));

// ---------------------------------------------------------------------------
// Threefry-2x32 (exactly jax/_src/prng.py), partitionable scheme (verified R1):
//   split  -> foldlike: key_j = cipher(key, (0, j))
//   bits32 -> per flat index n: bits1 ^ bits2 of cipher(key, (0, n))
// ---------------------------------------------------------------------------
__host__ __device__ __forceinline__ void tf2x32(uint32_t k0, uint32_t k1,
    uint32_t x0, uint32_t x1, uint32_t& o0, uint32_t& o1)
{
  const uint32_t k2 = k0 ^ k1 ^ 0x1BD11BDAu;
#define TFR(r) { x0 += x1; x1 = (x1 << r) | (x1 >> (32 - r)); x1 ^= x0; }
  x0 += k0; x1 += k1;
  TFR(13) TFR(15) TFR(26) TFR(6)
  x0 += k1; x1 += k2 + 1u;
  TFR(17) TFR(29) TFR(16) TFR(24)
  x0 += k2; x1 += k0 + 2u;
  TFR(13) TFR(15) TFR(26) TFR(6)
  x0 += k0; x1 += k1 + 3u;
  TFR(17) TFR(29) TFR(16) TFR(24)
  x0 += k1; x1 += k2 + 4u;
  TFR(13) TFR(15) TFR(26) TFR(6)
  x0 += k2; x1 += k0 + 5u;
#undef TFR
  o0 = x0; o1 = x1;
}

__device__ __forceinline__ uint32_t tf_bits32(uint32_t k0, uint32_t k1, uint32_t n)
{
  uint32_t a, b;
  tf2x32(k0, k1, 0u, n, a, b);
  return a ^ b;
}

// XLA ErfInv32 (Giles polynomial) — matches xla math.cc
__device__ __forceinline__ float erfinv_xla(float x)
{
  float w = -log1pf(-x * x);
  float p;
  if (w < 5.0f) {
    w = w - 2.5f;
    p = 2.81022636e-08f;
    p = fmaf(p, w, 3.43273939e-07f);
    p = fmaf(p, w, -3.5233877e-06f);
    p = fmaf(p, w, -4.39150654e-06f);
    p = fmaf(p, w, 0.00021858087f);
    p = fmaf(p, w, -0.00125372503f);
    p = fmaf(p, w, -0.00417768164f);
    p = fmaf(p, w, 0.246640727f);
    p = fmaf(p, w, 1.50140941f);
  } else {
    w = __builtin_amdgcn_sqrtf(w) - 3.0f;
    p = -0.000200214257f;
    p = fmaf(p, w, 0.000100950558f);
    p = fmaf(p, w, 0.00134934322f);
    p = fmaf(p, w, -0.00367342844f);
    p = fmaf(p, w, 0.00573950773f);
    p = fmaf(p, w, -0.0076224613f);
    p = fmaf(p, w, 0.00943887047f);
    p = fmaf(p, w, 1.00167406f);
    p = fmaf(p, w, 2.83297682f);
  }
  return p * x;
}

// ---------------------------------------------------------------------------
// Prep: per centroid row (p*512+c): fp16 hi/lo split + c2 (same fmaf order as
// R2-R4 — passed 3x), packed in one 272-byte row: [hi 128B | lo 128B | c2].
// ---------------------------------------------------------------------------
__global__ __launch_bounds__(256) void qvae_prep_kernel(
    const float* __restrict__ centroids, _Float16* __restrict__ cimg)
{
  const int idx = blockIdx.x * 256 + threadIdx.x;   // 0..4095
  const float* row = centroids + (size_t)idx * DCL;
  _Float16* orow = (_Float16*)((char*)cimg + (size_t)idx * ROWB);
  float s = 0.f;
#pragma unroll
  for (int d = 0; d < DCL; d += 4) {
    const float4 v = *(const float4*)(row + d);
    s = fmaf(v.x, v.x, s);
    s = fmaf(v.y, v.y, s);
    s = fmaf(v.z, v.z, s);
    s = fmaf(v.w, v.w, s);
  }
  *(float*)(orow + 128) = s;
#pragma unroll
  for (int d = 0; d < DCL; d += 8) {
    const float4 v0 = *(const float4*)(row + d);
    const float4 v1 = *(const float4*)(row + d + 4);
    const float vv[8] = { v0.x, v0.y, v0.z, v0.w, v1.x, v1.y, v1.z, v1.w };
    half8 hh, ll;
#pragma unroll
    for (int j = 0; j < 8; ++j) {
      const _Float16 h = (_Float16)vv[j];
      hh[j] = h;
      ll[j] = (_Float16)(vv[j] - (float)h);
    }
    *(half8*)(orow + d) = hh;
    *(half8*)(orow + 64 + d) = ll;
  }
}

// ---------------------------------------------------------------------------
// Main kernel — EXACT Round-3 submission (the 441us / VGPR-48 binary):
// block = 1 partition x 16 users, 4 waves. fp16-split MFMA cross with a
// SINGLE 6-MFMA accumulator chain (R4's accA/accB split raised VGPR 48->64,
// occupancy 55->44%, +5% time — do not reintroduce). Software-pipelined over
// 8 column-tiles (2-buffer prefetch from the L2-resident 272B-row image).
// Gumbel-argmax + softmax fused. C/D layout: col=lane&15, row=(lane>>4)*4+reg.
// ---------------------------------------------------------------------------
__global__ __launch_bounds__(256, 4) void qvae_main_kernel(
    const float* __restrict__ user_emb, const _Float16* __restrict__ cimg,
    const int* __restrict__ user_id, float* __restrict__ out_logits,
    int* __restrict__ sel, uint32_t kg0, uint32_t kg1)
{
  __shared__ float u2s[BTILE];
  __shared__ float zZ[4][BTILE];
  __shared__ float zS[4][BTILE];
  __shared__ int   zA[4][BTILE];

  const int p = blockIdx.y;
  const int bbase = blockIdx.x * BTILE;
  const int tid = threadIdx.x;
  const int w  = tid >> 6;    // wave 0..3
  const int l  = tid & 63;
  const int lr = l & 15;      // A-row / B-col lane index
  const int q  = l >> 4;      // k-quarter

  // ---- A fragments (16 users x 64 dims, fp16 split) + u2 ----
  const int uid = user_id[bbase + lr];
  const float* urow = user_emb + (size_t)uid * DTOT + p * DCL;
  float uf[16];
  {
    const float4 a0 = *(const float4*)(urow + q * 8);
    const float4 a1 = *(const float4*)(urow + q * 8 + 4);
    const float4 a2 = *(const float4*)(urow + 32 + q * 8);
    const float4 a3 = *(const float4*)(urow + 32 + q * 8 + 4);
    uf[0]=a0.x;  uf[1]=a0.y;  uf[2]=a0.z;  uf[3]=a0.w;
    uf[4]=a1.x;  uf[5]=a1.y;  uf[6]=a1.z;  uf[7]=a1.w;
    uf[8]=a2.x;  uf[9]=a2.y;  uf[10]=a2.z; uf[11]=a2.w;
    uf[12]=a3.x; uf[13]=a3.y; uf[14]=a3.z; uf[15]=a3.w;
  }
  half8 ah[2], al[2];
#pragma unroll
  for (int m = 0; m < 2; ++m)
#pragma unroll
    for (int j = 0; j < 8; ++j) {
      const float v = uf[m * 8 + j];
      const _Float16 h = (_Float16)v;
      ah[m][j] = h;
      al[m][j] = (_Float16)(v - (float)h);
    }
  {
    float s = 0.f;
#pragma unroll
    for (int i = 0; i < 16; ++i) s = fmaf(uf[i], uf[i], s);
    s += __shfl_xor(s, 16);
    s += __shfl_xor(s, 32);     // all lanes sharing lr now hold full u2[lr]
    if (tid < BTILE) u2s[tid] = s;
  }
  __syncthreads();
  float u2r[4];
  {
    const float4 uv = *(const float4*)&u2s[q * 4];
    u2r[0]=uv.x; u2r[1]=uv.y; u2r[2]=uv.z; u2r[3]=uv.w;
  }

  // per-wave/lane bases: cluster col = wcol + CDELT(i); threefry n = nbw + ...
  const int wcol = w * 32 + lr;
  const uint32_t nbw =
      ((uint32_t)(bbase + q * 4) * 8u + (uint32_t)p) * 512u + (uint32_t)wcol;
  const char* cb = (const char*)cimg;
  const uint32_t rowoff =
      ((uint32_t)p * NCLUS + (uint32_t)wcol) * (uint32_t)ROWB + (uint32_t)q * 16u;

  float ereg[32];
  float Zs[4]  = { 0.f, 0.f, 0.f, 0.f };
  float smx[4] = { -3.4e38f, -3.4e38f, -3.4e38f, -3.4e38f };
  int   sag[4] = { 0, 0, 0, 0 };

  // cluster-col delta for pipeline step i (tile = (i>>1)*8 + w*2 + (i&1))
#define CDELT(i) ((((i) >> 1) * 128) + (((i) & 1) * 16))
#define BDELT(i) ((uint32_t)(CDELT(i)) * (uint32_t)ROWB)

#define LOADT(S, i)                                                           \
  {                                                                           \
    const uint32_t vo = rowoff + BDELT(i);                                    \
    bh0##S = *(const half8*)(cb + vo);                                        \
    bh1##S = *(const half8*)(cb + vo + 64);                                   \
    bl0##S = *(const half8*)(cb + vo + 128);                                  \
    bl1##S = *(const half8*)(cb + vo + 192);                                  \
    c2##S  = *(const float*)(cb + (vo - q * 16) + 256);                       \
  }

#define COMPT(S, i)                                                           \
  {                                                                           \
    f32x4 acc = { 0.f, 0.f, 0.f, 0.f };                                       \
    acc = __builtin_amdgcn_mfma_f32_16x16x32_f16(ah[0], bh0##S, acc, 0, 0, 0);\
    acc = __builtin_amdgcn_mfma_f32_16x16x32_f16(ah[1], bh1##S, acc, 0, 0, 0);\
    acc = __builtin_amdgcn_mfma_f32_16x16x32_f16(al[0], bh0##S, acc, 0, 0, 0);\
    acc = __builtin_amdgcn_mfma_f32_16x16x32_f16(al[1], bh1##S, acc, 0, 0, 0);\
    acc = __builtin_amdgcn_mfma_f32_16x16x32_f16(ah[0], bl0##S, acc, 0, 0, 0);\
    acc = __builtin_amdgcn_mfma_f32_16x16x32_f16(ah[1], bl1##S, acc, 0, 0, 0);\
    const uint32_t ncol = nbw + (uint32_t)CDELT(i);                           \
    const int colc = wcol + CDELT(i);                                         \
    _Pragma("unroll")                                                         \
    for (int r = 0; r < 4; ++r) {                                             \
      const float u2c2 = __fadd_rn(u2r[r], c2##S);                            \
      const float d2 = fmaxf(fmaf(-2.0f, acc[r], u2c2), 0.0f);                \
      const float qd = __builtin_amdgcn_sqrtf(__fadd_rn(d2, 1e-12f));         \
      const uint32_t bits = tf_bits32(kg0, kg1, ncol + (uint32_t)r * 4096u);  \
      const float u01 = __uint_as_float((bits >> 9) | 0x3f800000u) - 1.0f;    \
      const float gu = __fadd_rn(u01, 1e-10f);  /* >=1e-10 always: fmax dropped (exact) */ \
      const float g = -__logf(-__logf(gu));                                   \
      const float sc = __fsub_rn(g, qd);                                      \
      if (sc > smx[r]) { smx[r] = sc; sag[r] = colc; }                        \
      const float e = __expf(-qd);              /* exp(nd), no max-sub */     \
      ereg[(i) * 4 + r] = e;                                                  \
      Zs[r] = __fadd_rn(Zs[r], e);                                            \
    }                                                                         \
  }

  half8 bh0A, bh1A, bl0A, bl1A; float c2A;
  half8 bh0B, bh1B, bl0B, bl1B; float c2B;
  LOADT(A, 0)
  LOADT(B, 1)
  COMPT(A, 0)
  LOADT(A, 2)
  COMPT(B, 1)
  LOADT(B, 3)
  COMPT(A, 2)
  LOADT(A, 4)
  COMPT(B, 3)
  LOADT(B, 5)
  COMPT(A, 4)
  LOADT(A, 6)
  COMPT(B, 5)
  LOADT(B, 7)
  COMPT(A, 6)
  COMPT(B, 7)

  // reduce across the 16 lanes (same q) holding this row set
#pragma unroll
  for (int m = 1; m < 16; m <<= 1) {
#pragma unroll
    for (int r = 0; r < 4; ++r) {
      Zs[r] += __shfl_xor(Zs[r], m);
      const float os = __shfl_xor(smx[r], m);
      const int   oa = __shfl_xor(sag[r], m);
      if (os > smx[r] || (os == smx[r] && oa < sag[r])) { smx[r] = os; sag[r] = oa; }
    }
  }
  if (lr == 0) {
#pragma unroll
    for (int r = 0; r < 4; ++r) {
      zZ[w][q * 4 + r] = Zs[r];
      zS[w][q * 4 + r] = smx[r];
      zA[w][q * 4 + r] = sag[r];
    }
  }
  __syncthreads();

  // cross-wave combine (4 waves hold different cluster columns of same rows)
  float Zf[4]  = { 0.f, 0.f, 0.f, 0.f };
  float smf[4] = { -3.4e38f, -3.4e38f, -3.4e38f, -3.4e38f };
  int   saf[4] = { 0, 0, 0, 0 };
#pragma unroll
  for (int wv = 0; wv < 4; ++wv) {
    const float4 zz = *(const float4*)&zZ[wv][q * 4];
    const float4 ss = *(const float4*)&zS[wv][q * 4];
    const int4   aa = *(const int4*)&zA[wv][q * 4];
    const float zv[4] = { zz.x, zz.y, zz.z, zz.w };
    const float sv[4] = { ss.x, ss.y, ss.z, ss.w };
    const int   av[4] = { aa.x, aa.y, aa.z, aa.w };
#pragma unroll
    for (int r = 0; r < 4; ++r) {
      Zf[r] = __fadd_rn(Zf[r], zv[r]);
      if (sv[r] > smf[r] || (sv[r] == smf[r] && av[r] < saf[r])) {
        smf[r] = sv[r]; saf[r] = av[r];
      }
    }
  }

  float inv[4];
#pragma unroll
  for (int r = 0; r < 4; ++r) inv[r] = __builtin_amdgcn_rcpf(Zf[r]);

  float* obase = out_logits + ((size_t)(bbase + q * 4) * 8 + p) * 512 + wcol;
#pragma unroll
  for (int i = 0; i < 8; ++i)
#pragma unroll
    for (int r = 0; r < 4; ++r)
      obase[(size_t)r * 4096 + CDELT(i)] = ereg[i * 4 + r] * inv[r];

  if (w == 0 && lr == 0) {
#pragma unroll
    for (int r = 0; r < 4; ++r)
      sel[(bbase + q * 4 + r) * NPART + p] = saf[r];
  }
#undef CDELT
#undef BDELT
#undef LOADT
#undef COMPT
}

// ---------------------------------------------------------------------------
// Score kernel (unchanged, passed 7x): one 64-lane wave per b.
// ---------------------------------------------------------------------------
__global__ __launch_bounds__(256) void qvae_score_kernel(
    const float* __restrict__ centroids, const float* __restrict__ item_mu,
    const float* __restrict__ item_logvar, const int* __restrict__ item_id,
    const int* __restrict__ sel, float* __restrict__ out_score,
    uint32_t ke0, uint32_t ke1)
{
  const int lane = threadIdx.x & 63;
  const int b = blockIdx.x * 4 + (threadIdx.x >> 6);
  const int iid = item_id[b];
  const int pp = lane >> 3;
  const int sc = sel[b * NPART + pp];

  const float* cen = centroids + ((size_t)pp * NCLUS + sc) * DCL + (lane & 7) * 8;
  const float* mu = item_mu + (size_t)iid * DTOT + lane * 8;
  const float* lv = item_logvar + (size_t)iid * DTOT + lane * 8;

  const float4 m0 = *(const float4*)mu;
  const float4 m1 = *(const float4*)(mu + 4);
  const float4 l0 = *(const float4*)lv;
  const float4 l1 = *(const float4*)(lv + 4);
  const float4 q0 = *(const float4*)cen;
  const float4 q1 = *(const float4*)(cen + 4);
  const float mua[8] = { m0.x, m0.y, m0.z, m0.w, m1.x, m1.y, m1.z, m1.w };
  const float lva[8] = { l0.x, l0.y, l0.z, l0.w, l1.x, l1.y, l1.z, l1.w };
  const float cna[8] = { q0.x, q0.y, q0.z, q0.w, q1.x, q1.y, q1.z, q1.w };

  const float LO = __int_as_float(0xBF7FFFFFu);   // nextafter(-1,0)
  const float SQ2 = __int_as_float(0x3FB504F3u);  // float(sqrt(2))
  const uint32_t nb = (uint32_t)b * 512u + (uint32_t)lane * 8u;

  float acc = 0.f;
#pragma unroll
  for (int k = 0; k < 8; ++k) {
    const uint32_t bits = tf_bits32(ke0, ke1, nb + (uint32_t)k);
    const float u01 = __uint_as_float((bits >> 9) | 0x3f800000u) - 1.0f;
    const float uu = fmaxf(LO, __fadd_rn(__fmul_rn(u01, 2.0f), LO));
    const float eps = __fmul_rn(SQ2, erfinv_xla(uu));
    const float sd = __expf(__fmul_rn(0.5f, lva[k]));
    const float it = __fadd_rn(__fmul_rn(eps, sd), mua[k]);
    acc = fmaf(cna[k], it, acc);
  }
#pragma unroll
  for (int m = 1; m < 64; m <<= 1) acc += __shfl_xor(acc, m);
  if (lane == 0) out_score[b] = acc;
}

// ---------------------------------------------------------------------------
extern "C" void kernel_launch(void* const* d_in, const int* in_sizes, int n_in,
                              void* d_out, int out_size, void* d_ws, size_t ws_size,
                              hipStream_t stream)
{
  (void)in_sizes; (void)n_in; (void)out_size; (void)ws_size;

  const float* user_emb    = (const float*)d_in[0];
  const float* centroids   = (const float*)d_in[1];
  const float* item_mu     = (const float*)d_in[2];
  const float* item_logvar = (const float*)d_in[3];
  const int*   user_id     = (const int*)d_in[4];
  const int*   item_id     = (const int*)d_in[5];

  float* out_score  = (float*)d_out;            // [B]
  float* out_logits = (float*)d_out + B_TOT;    // [B,P,C]

  // ws layout: sel [B*P] int (1 MB) | cimg [P*C][272B] (1.09 MB, 16B-aligned)
  int*       sel  = (int*)d_ws;
  _Float16*  cimg = (_Float16*)((char*)d_ws + (size_t)B_TOT * NPART * 4);

  // host-side key derivation: key(42) = (0,42); foldlike split
  uint32_t kg0, kg1, ke0, ke1;
  tf2x32(0u, 42u, 0u, 0u, kg0, kg1);
  tf2x32(0u, 42u, 0u, 1u, ke0, ke1);

  qvae_prep_kernel<<<NPART * NCLUS / 256, 256, 0, stream>>>(centroids, cimg);

  dim3 g1(B_TOT / BTILE, NPART);
  qvae_main_kernel<<<g1, 256, 0, stream>>>(user_emb, cimg, user_id,
                                           out_logits, sel, kg0, kg1);
  qvae_score_kernel<<<B_TOT / 4, 256, 0, stream>>>(centroids, item_mu, item_logvar,
                                                   item_id, sel, out_score, ke0, ke1);
}